// Round 2
// baseline (1352.712 us; speedup 1.0000x reference)
//
#include <hip/hip_runtime.h>
#include <hip/hip_bf16.h>
#include <math.h>

// ---- problem constants (match reference setup) ----
constexpr int DD   = 768;    // feature dim
constexpr int NSUP = 1024;   // support rows (WAY*SHOT)
constexpr int NQQ  = 2048;   // queries
constexpr int NC   = 64;     // classes (way)
constexpr int SHOT = 16;
constexpr int RR   = 18;     // Woodbury rank = SHOT + 2
constexpr float REGP = 0.5f;
constexpr int DDS = DD * DD;
constexpr int NROWS = NQQ + NSUP + 1 + NC; // stacked transformed rows: [TQ; TX; Tm; Tmu]

// ---------------------------------------------------------------------------
// L = diag(|triu_diag|) + strictly-lower(triu_lower)
__global__ __launch_bounds__(256) void build_L(const float* __restrict__ tdiag,
                                               const float* __restrict__ tlow,
                                               float* __restrict__ Lm) {
    int idx = blockIdx.x * 256 + threadIdx.x;
    if (idx >= DDS) return;
    int i = idx / DD, j = idx % DD;
    float v = (i == j) ? fabsf(tdiag[i]) : (i > j ? tlow[idx] : 0.f);
    Lm[idx] = v;
}

// ---------------------------------------------------------------------------
// per-class: gather indices, compute mu_c into mmu rows 1..64; block0 copies m to row 0
__global__ __launch_bounds__(256) void class_stats(const float* __restrict__ Xs,
                                                   const float* __restrict__ m,
                                                   const int* __restrict__ labels,
                                                   const float* __restrict__ kappa,
                                                   float* __restrict__ mmu,
                                                   int* __restrict__ cls_idx,
                                                   int* __restrict__ cls_n) {
    int c = blockIdx.x;
    __shared__ int lidx[SHOT];
    __shared__ int lcount;
    if (threadIdx.x == 0) lcount = 0;
    __syncthreads();
    for (int n = threadIdx.x; n < NSUP; n += 256) {
        if (labels[n] == c) {
            int pos = atomicAdd(&lcount, 1);
            if (pos < SHOT) lidx[pos] = n;
        }
    }
    __syncthreads();
    int cnt = lcount < SHOT ? lcount : SHOT;
    if (threadIdx.x < SHOT) cls_idx[c * SHOT + threadIdx.x] = (threadIdx.x < cnt) ? lidx[threadIdx.x] : 0;
    if (threadIdx.x == 0) cls_n[c] = cnt;
    float kap = fabsf(kappa[0]) + 1e-6f;
    float fn = (float)cnt;
    float wm = kap / (kap + fn);
    float wx = 1.f / (kap + fn);            // (fn/(kap+fn)) * (sum/fn) = sum * wx
    if (c == 0) {
        for (int d = threadIdx.x; d < DD; d += 256) mmu[d] = m[d];
    }
    for (int d = threadIdx.x; d < DD; d += 256) {
        float s = 0.f;
        for (int t = 0; t < cnt; ++t) s += Xs[(size_t)lidx[t] * DD + d];
        mmu[(size_t)(1 + c) * DD + d] = wm * m[d] + wx * s;
    }
}

// ---------------------------------------------------------------------------
// invert the 12 diagonal 64x64 blocks of lower-triangular L into G
__global__ __launch_bounds__(64) void trtri_diag(const float* __restrict__ Lm,
                                                 float* __restrict__ G) {
    int b = blockIdx.x;
    __shared__ float lt[64][65];
    __shared__ float xt[64][65];
    int tid = threadIdx.x; // 64 threads
    for (int i = 0; i < 64; ++i) {
        lt[i][tid] = Lm[((size_t)b * 64 + i) * DD + b * 64 + tid];
        xt[i][tid] = 0.f;
    }
    __syncthreads();
    int j = tid; // column j, independent per thread
    xt[j][j] = 1.f / lt[j][j];
    for (int i = j + 1; i < 64; ++i) {
        float s = 0.f;
        for (int k = j; k < i; ++k) s += lt[i][k] * xt[k][j];
        xt[i][j] = -s / lt[i][i];
    }
    __syncthreads();
    for (int i = 0; i < 64; ++i)
        G[((size_t)b * 64 + i) * DD + b * 64 + tid] = xt[i][tid];
}

// off-diagonal TRTRI wavefront step s: G[j+s][j] = -G_ii * sum_{k=j}^{j+s-1} L[i][k] G[k][j]
__global__ __launch_bounds__(256) void trtri_off(const float* __restrict__ Lm,
                                                 float* __restrict__ G, int s) {
    int j = blockIdx.x;
    int i = j + s;
    __shared__ float t0[64][65];
    __shared__ float t1[64][65];
    int tid = threadIdx.x;
    int tr = tid >> 4, tc = tid & 15;
    float acc[4][4] = {};
    for (int kb = j; kb < i; ++kb) {
        for (int t = tid; t < 64 * 64; t += 256) {
            int r = t >> 6, cc = t & 63;
            t0[r][cc] = Lm[((size_t)i * 64 + r) * DD + kb * 64 + cc];
            t1[r][cc] = G[((size_t)kb * 64 + r) * DD + j * 64 + cc];
        }
        __syncthreads();
        for (int k = 0; k < 64; ++k) {
            float a[4], b[4];
#pragma unroll
            for (int x = 0; x < 4; ++x) { a[x] = t0[tr * 4 + x][k]; b[x] = t1[k][tc * 4 + x]; }
#pragma unroll
            for (int x = 0; x < 4; ++x)
#pragma unroll
                for (int y = 0; y < 4; ++y) acc[x][y] += a[x] * b[y];
        }
        __syncthreads();
    }
    // t0 <- G[i][i] (tri inverse diag block), t1 <- acc
    for (int t = tid; t < 64 * 64; t += 256) {
        int r = t >> 6, cc = t & 63;
        t0[r][cc] = G[((size_t)i * 64 + r) * DD + i * 64 + cc];
    }
#pragma unroll
    for (int x = 0; x < 4; ++x)
#pragma unroll
        for (int y = 0; y < 4; ++y) t1[tr * 4 + x][tc * 4 + y] = acc[x][y];
    __syncthreads();
    float out4[4][4] = {};
    for (int k = 0; k < 64; ++k) {
        float a[4], b[4];
#pragma unroll
        for (int x = 0; x < 4; ++x) { a[x] = t0[tr * 4 + x][k]; b[x] = t1[k][tc * 4 + x]; }
#pragma unroll
        for (int x = 0; x < 4; ++x)
#pragma unroll
            for (int y = 0; y < 4; ++y) out4[x][y] += a[x] * b[y];
    }
#pragma unroll
    for (int x = 0; x < 4; ++x)
#pragma unroll
        for (int y = 0; y < 4; ++y)
            G[((size_t)i * 64 + tr * 4 + x) * DD + j * 64 + tc * 4 + y] = -out4[x][y];
}

// ---------------------------------------------------------------------------
// C[M][Nn] = A[M][K] * B[Nn][K]^T   (B row-major = "NT" GEMM). TRI: B is lower
// triangular (row n has k<=n) -> skip k-tiles beyond the column tile.
template <bool TRI>
__global__ __launch_bounds__(256) void gemm_nt(const float* __restrict__ A,
                                               const float* __restrict__ B,
                                               float* __restrict__ Cc,
                                               int M, int Nn, int K) {
    __shared__ __align__(16) float As[32][68];
    __shared__ __align__(16) float Bs[32][68];
    int bm = blockIdx.x, bn = blockIdx.y;
    int row0 = bm * 64, col0 = bn * 64;
    int tid = threadIdx.x;
    int tr = tid >> 4, tc = tid & 15;
    float acc[4][4] = {};
    int kmax = TRI ? ((bn + 1) * 64 < K ? (bn + 1) * 64 : K) : K;
    for (int k0 = 0; k0 < kmax; k0 += 32) {
        for (int t = tid; t < 64 * 32; t += 256) {
            int r = t >> 5, kk = t & 31;
            int ar = row0 + r;
            As[kk][r] = (ar < M) ? A[(size_t)ar * K + k0 + kk] : 0.f;
            int br = col0 + r;
            Bs[kk][r] = (br < Nn) ? B[(size_t)br * K + k0 + kk] : 0.f;
        }
        __syncthreads();
#pragma unroll
        for (int kk = 0; kk < 32; ++kk) {
            float4 av = *(const float4*)(&As[kk][tr << 2]);
            float4 bv = *(const float4*)(&Bs[kk][tc << 2]);
            float a[4] = {av.x, av.y, av.z, av.w};
            float b[4] = {bv.x, bv.y, bv.z, bv.w};
#pragma unroll
            for (int x = 0; x < 4; ++x)
#pragma unroll
                for (int y = 0; y < 4; ++y) acc[x][y] += a[x] * b[y];
        }
        __syncthreads();
    }
#pragma unroll
    for (int x = 0; x < 4; ++x) {
        int r = row0 + tr * 4 + x;
        if (r >= M) continue;
#pragma unroll
        for (int y = 0; y < 4; ++y) {
            int cc2 = col0 + tc * 4 + y;
            if (cc2 < Nn) Cc[(size_t)r * Nn + cc2] = acc[x][y];
        }
    }
}

// ---------------------------------------------------------------------------
// Vt row (c*18+i): i<16 -> TX[idx], i==16 -> sqrt(kap)*Tm, i==17 -> sqrt(kap+Nc)*Tmu_c
__global__ __launch_bounds__(256) void build_V(const float* __restrict__ Trows,
                                               const int* __restrict__ cls_idx,
                                               const int* __restrict__ cls_n,
                                               const float* __restrict__ kappa,
                                               float* __restrict__ Vt) {
    int row = blockIdx.x;
    int c = row / RR, i = row % RR;
    int cnt = cls_n[c];
    float kap = fabsf(kappa[0]) + 1e-6f;
    size_t srow;
    float sc = 1.f;
    if (i < SHOT) {
        if (i >= cnt) {
            for (int d = threadIdx.x; d < DD; d += 256) Vt[(size_t)row * DD + d] = 0.f;
            return;
        }
        srow = (size_t)NQQ + cls_idx[c * SHOT + i];
    } else if (i == SHOT) {
        srow = NQQ + NSUP;
        sc = sqrtf(kap);
    } else {
        srow = (size_t)NQQ + NSUP + 1 + c;
        sc = sqrtf(kap + (float)cnt);
    }
    for (int d = threadIdx.x; d < DD; d += 256)
        Vt[(size_t)row * DD + d] = sc * Trows[srow * DD + d];
}

// ---------------------------------------------------------------------------
// per class: M = J + Vt Vt^T (fp64), invert (GJ w/ pivoting, fp64), h, consts.
__global__ __launch_bounds__(256) void build_M(const float* __restrict__ Trows,
                                               const float* __restrict__ mmu,
                                               const float* __restrict__ Vt,
                                               const float* __restrict__ tdiag,
                                               const float* __restrict__ kappa,
                                               const float* __restrict__ nu,
                                               const int* __restrict__ cls_n,
                                               float* __restrict__ consts,
                                               float* __restrict__ hbuf,
                                               float* __restrict__ MinvO) {
    int c = blockIdx.x;
    __shared__ double Md[RR][RR];
    __shared__ double aug[RR][2 * RR];
    __shared__ double colk[RR];
    __shared__ double red[4];
    __shared__ double gj_logdet;
    __shared__ float hs[RR];
    __shared__ float ng2t_s, mu2_s;
    int tid = threadIdx.x;
    int wave = tid >> 6, lane = tid & 63;
    const float* Vc = Vt + (size_t)c * RR * DD;
    const float* Tmu = Trows + (size_t)(NQQ + NSUP + 1 + c) * DD;
    const float* mu_raw = mmu + (size_t)(1 + c) * DD;

    // dot-product tasks: 0..323 = M[i][j] (skip i>j); 324..341 = h[i]; 342 = ||Tmu||^2; 343 = ||mu||^2
    for (int p = wave; p < RR * RR + RR + 2; p += 4) {
        const float *va, *vb;
        if (p < RR * RR) {
            int i = p / RR, j = p % RR;
            if (i > j) continue;
            va = Vc + (size_t)i * DD; vb = Vc + (size_t)j * DD;
        } else if (p < RR * RR + RR) {
            va = Vc + (size_t)(p - RR * RR) * DD; vb = Tmu;
        } else if (p == RR * RR + RR) {
            va = Tmu; vb = Tmu;
        } else {
            va = mu_raw; vb = mu_raw;
        }
        double s = 0.0;
        for (int d = lane; d < DD; d += 64) s += (double)va[d] * (double)vb[d];
        for (int off = 32; off; off >>= 1) s += __shfl_down(s, off);
        if (lane == 0) {
            if (p < RR * RR) { int i = p / RR, j = p % RR; Md[i][j] = s; Md[j][i] = s; }
            else if (p < RR * RR + RR) hs[p - RR * RR] = (float)s;
            else if (p == RR * RR + RR) ng2t_s = (float)s;
            else mu2_s = (float)s;
        }
    }
    // sum log diag(L) (= log|tdiag|)
    double sl = 0.0;
    for (int k = tid; k < DD; k += 256) sl += log((double)fabsf(tdiag[k]));
    for (int off = 32; off; off >>= 1) sl += __shfl_down(sl, off);
    if (lane == 0) red[wave] = sl;
    __syncthreads();

    if (tid == 0) {
        for (int i = 0; i < RR - 1; ++i) Md[i][i] += 1.0;
        Md[RR - 1][RR - 1] -= 1.0;
        gj_logdet = 0.0;
    }
    __syncthreads();
    for (int t = tid; t < RR * 2 * RR; t += 256) {
        int r2 = t / (2 * RR), j2 = t % (2 * RR);
        aug[r2][j2] = (j2 < RR) ? Md[r2][j2] : ((j2 - RR == r2) ? 1.0 : 0.0);
    }
    __syncthreads();
    for (int k = 0; k < RR; ++k) {
        if (tid == 0) {
            int piv = k; double best = fabs(aug[k][k]);
            for (int r2 = k + 1; r2 < RR; ++r2) {
                double v = fabs(aug[r2][k]);
                if (v > best) { best = v; piv = r2; }
            }
            if (piv != k) {
                for (int j2 = 0; j2 < 2 * RR; ++j2) {
                    double tmp = aug[k][j2]; aug[k][j2] = aug[piv][j2]; aug[piv][j2] = tmp;
                }
            }
            double pv = aug[k][k];
            gj_logdet += log(fabs(pv));
            double inv = 1.0 / pv;
            for (int j2 = 0; j2 < 2 * RR; ++j2) aug[k][j2] *= inv;
        }
        __syncthreads();
        if (tid < RR) colk[tid] = (tid == k) ? 0.0 : aug[tid][k];
        __syncthreads();
        for (int t = tid; t < RR * 2 * RR; t += 256) {
            int r2 = t / (2 * RR), j2 = t % (2 * RR);
            if (r2 != k) aug[r2][j2] -= colk[r2] * aug[k][j2];
        }
        __syncthreads();
    }
    if (tid == 0) {
        double sumlog = red[0] + red[1] + red[2] + red[3];
        double kap = fabs((double)kappa[0]) + 1e-6;
        double nu_ = fmax((double)nu[0], (double)(DD - 1) + 1e-6);
        double fn = (double)cls_n[c];
        double common = nu_ + fn + 1.0 - (double)DD;
        double scale = (kap + fn + 1.0) / (common * (kap + fn));
        // logdet(sigma) = D log scale + 2*sum(log Ldiag) + log(det(J)*det(M)); det(J)*det(M)>0
        double logdet_sigma = (double)DD * log(scale) + 2.0 * sumlog + gj_logdet;
        double bias = lgamma(0.5 * (common + DD)) - lgamma(0.5 * common)
                    - 0.5 * DD * log(common) - 0.5 * logdet_sigma;
        consts[c * 8 + 0] = (float)((1.0 - (double)REGP) / scale);
        consts[c * 8 + 1] = (float)common;
        consts[c * 8 + 2] = (float)(0.5 * (common + DD));
        consts[c * 8 + 3] = (float)bias;
        consts[c * 8 + 4] = (float)(1.0 / sqrt(kap + fn));
        consts[c * 8 + 5] = ng2t_s;
        consts[c * 8 + 6] = mu2_s;
        consts[c * 8 + 7] = 0.f;
    }
    __syncthreads();
    for (int t = tid; t < RR * RR; t += 256)
        MinvO[(size_t)c * RR * RR + t] = (float)aug[t / RR][RR + t % RR];
    if (tid < RR) hbuf[c * RR + tid] = hs[tid];
}

// ---------------------------------------------------------------------------
__global__ __launch_bounds__(256) void query_norms(const float* __restrict__ Qx,
                                                   const float* __restrict__ Trows,
                                                   float* __restrict__ q2,
                                                   float* __restrict__ nq2t) {
    int q = blockIdx.x * 4 + (threadIdx.x >> 6);
    int lane = threadIdx.x & 63;
    float s1 = 0.f, s2 = 0.f;
    for (int d = lane; d < DD; d += 64) {
        float a = Qx[(size_t)q * DD + d]; s1 += a * a;
        float b = Trows[(size_t)q * DD + d]; s2 += b * b;
    }
    for (int off = 32; off; off >>= 1) { s1 += __shfl_down(s1, off); s2 += __shfl_down(s2, off); }
    if (lane == 0) { q2[q] = s1; nq2t[q] = s2; }
}

// ---------------------------------------------------------------------------
__global__ __launch_bounds__(256) void final_kernel(const float* __restrict__ P,
                                                    const float* __restrict__ dotqmu,
                                                    const float* __restrict__ q2,
                                                    const float* __restrict__ nq2t,
                                                    const float* __restrict__ consts,
                                                    const float* __restrict__ hbuf,
                                                    const float* __restrict__ Minv,
                                                    float* __restrict__ out) {
    int c = blockIdx.x, qt = blockIdx.y;
    __shared__ float Ms[RR][RR];
    __shared__ float hlds[RR];
    __shared__ float cs[8];
    int tid = threadIdx.x;
    for (int t = tid; t < RR * RR; t += 256) Ms[t / RR][t % RR] = Minv[(size_t)c * RR * RR + t];
    if (tid < RR) hlds[tid] = hbuf[c * RR + tid];
    if (tid < 8) cs[tid] = consts[c * 8 + tid];
    __syncthreads();
    int q = qt * 256 + tid;
    const float* Pq = P + (size_t)q * (NC * RR) + c * RR;
    float p[RR];
    float p17raw = Pq[RR - 1];
#pragma unroll
    for (int i = 0; i < RR; ++i) p[i] = Pq[i] - hlds[i];
    float quad = 0.f;
#pragma unroll
    for (int i = 0; i < RR; ++i) {
        float t = 0.f;
#pragma unroll
        for (int j = 0; j < RR; ++j) t += Ms[i][j] * p[j];
        quad += p[i] * t;
    }
    float w1 = cs[0], common = cs[1], coef = cs[2], bias = cs[3];
    float inv_s17 = cs[4], ng2t = cs[5], mu2 = cs[6];
    float Gu2 = nq2t[q] - 2.f * p17raw * inv_s17 + ng2t;
    float u2 = q2[q] - 2.f * dotqmu[(size_t)q * NC + c] + mu2;
    float dist = w1 * (Gu2 - quad) + REGP * u2;
    out[(size_t)q * NC + c] = bias - coef * log1pf(dist / common);
}

// ---------------------------------------------------------------------------
extern "C" void kernel_launch(void* const* d_in, const int* in_sizes, int n_in,
                              void* d_out, int out_size, void* d_ws, size_t ws_size,
                              hipStream_t stream) {
    const float* Xs    = (const float*)d_in[0];
    const float* Qx    = (const float*)d_in[1];
    const float* m     = (const float*)d_in[2];
    const float* kappa = (const float*)d_in[3];
    const float* nu    = (const float*)d_in[4];
    const float* tdiag = (const float*)d_in[5];
    const float* tlow  = (const float*)d_in[6];
    const int* labels  = (const int*)d_in[7];
    float* out = (float*)d_out;

    float* ws = (float*)d_ws;
    float* Lm     = ws;                                  // D*D
    float* G      = Lm + DDS;                            // D*D
    float* mmu    = G + DDS;                             // (NC+1)*D  [m; mu_0..63]
    float* Trows  = mmu + (size_t)(NC + 1) * DD;         // NROWS*D   [TQ; TX; Tm; Tmu]
    float* Vt     = Trows + (size_t)NROWS * DD;          // NC*RR*D
    float* P      = Vt + (size_t)NC * RR * DD;           // NQ*NC*RR
    float* dotqmu = P + (size_t)NQQ * NC * RR;           // NQ*NC
    float* q2     = dotqmu + (size_t)NQQ * NC;           // NQ
    float* nq2t   = q2 + NQQ;                            // NQ
    float* consts = nq2t + NQQ;                          // NC*8
    float* hbuf   = consts + NC * 8;                     // NC*RR
    float* MinvB  = hbuf + NC * RR;                      // NC*RR*RR
    int* cls_idx  = (int*)(MinvB + (size_t)NC * RR * RR);// NC*SHOT
    int* cls_n    = cls_idx + NC * SHOT;                 // NC

    build_L<<<(DDS + 255) / 256, 256, 0, stream>>>(tdiag, tlow, Lm);
    class_stats<<<NC, 256, 0, stream>>>(Xs, m, labels, kappa, mmu, cls_idx, cls_n);
    trtri_diag<<<12, 64, 0, stream>>>(Lm, G);
    for (int s = 1; s <= 11; ++s)
        trtri_off<<<12 - s, 256, 0, stream>>>(Lm, G, s);
    // transformed rows: X @ G^T (G lower triangular)
    gemm_nt<true><<<dim3(NQQ / 64, DD / 64), 256, 0, stream>>>(Qx, G, Trows, NQQ, DD, DD);
    gemm_nt<true><<<dim3(NSUP / 64, DD / 64), 256, 0, stream>>>(Xs, G, Trows + (size_t)NQQ * DD, NSUP, DD, DD);
    gemm_nt<true><<<dim3(2, DD / 64), 256, 0, stream>>>(mmu, G, Trows + (size_t)(NQQ + NSUP) * DD, NC + 1, DD, DD);
    build_V<<<NC * RR, 256, 0, stream>>>(Trows, cls_idx, cls_n, kappa, Vt);
    build_M<<<NC, 256, 0, stream>>>(Trows, mmu, Vt, tdiag, kappa, nu, cls_n, consts, hbuf, MinvB);
    query_norms<<<NQQ / 4, 256, 0, stream>>>(Qx, Trows, q2, nq2t);
    gemm_nt<false><<<dim3(NQQ / 64, (NC * RR) / 64), 256, 0, stream>>>(Trows, Vt, P, NQQ, NC * RR, DD);
    gemm_nt<false><<<dim3(NQQ / 64, 1), 256, 0, stream>>>(Qx, mmu + DD, dotqmu, NQQ, NC, DD);
    final_kernel<<<dim3(NC, NQQ / 256), 256, 0, stream>>>(P, dotqmu, q2, nq2t, consts, hbuf, MinvB, out);
}

// Round 8
// 948.902 us; speedup vs baseline: 1.4256x; 1.4256x over previous
//
#include <hip/hip_runtime.h>
#include <hip/hip_bf16.h>
#include <math.h>

// ---- problem constants (match reference setup) ----
constexpr int DD   = 768;    // feature dim
constexpr int NSUP = 1024;   // support rows (WAY*SHOT)
constexpr int NQQ  = 2048;   // queries
constexpr int NC   = 64;     // classes (way)
constexpr int SHOT = 16;
constexpr int RR   = 18;     // Woodbury rank = SHOT + 2
constexpr float REGP = 0.5f;
constexpr int DDS = DD * DD;
constexpr int NROWS = NQQ + NSUP + 1 + NC; // stacked transformed rows: [TQ; TX; Tm; Tmu]
constexpr int PW   = 16;     // TRTRI panel width
constexpr int NPB  = DD / PW;// 48 panel blocks

// ---------------------------------------------------------------------------
// L = diag(|triu_diag|) + strictly-lower(triu_lower)
__global__ __launch_bounds__(256) void build_L(const float* __restrict__ tdiag,
                                               const float* __restrict__ tlow,
                                               float* __restrict__ Lm) {
    int idx = blockIdx.x * 256 + threadIdx.x;
    if (idx >= DDS) return;
    int i = idx / DD, j = idx % DD;
    float v = (i == j) ? fabsf(tdiag[i]) : (i > j ? tlow[idx] : 0.f);
    Lm[idx] = v;
}

// ---------------------------------------------------------------------------
// per-class: gather indices, compute mu_c into mmu rows 1..64; block0 copies m to row 0
__global__ __launch_bounds__(256) void class_stats(const float* __restrict__ Xs,
                                                   const float* __restrict__ m,
                                                   const int* __restrict__ labels,
                                                   const float* __restrict__ kappa,
                                                   float* __restrict__ mmu,
                                                   int* __restrict__ cls_idx,
                                                   int* __restrict__ cls_n) {
    int c = blockIdx.x;
    __shared__ int lidx[SHOT];
    __shared__ int lcount;
    if (threadIdx.x == 0) lcount = 0;
    __syncthreads();
    for (int n = threadIdx.x; n < NSUP; n += 256) {
        if (labels[n] == c) {
            int pos = atomicAdd(&lcount, 1);
            if (pos < SHOT) lidx[pos] = n;
        }
    }
    __syncthreads();
    int cnt = lcount < SHOT ? lcount : SHOT;
    if (threadIdx.x < SHOT) cls_idx[c * SHOT + threadIdx.x] = (threadIdx.x < cnt) ? lidx[threadIdx.x] : 0;
    if (threadIdx.x == 0) cls_n[c] = cnt;
    float kap = fabsf(kappa[0]) + 1e-6f;
    float fn = (float)cnt;
    float wm = kap / (kap + fn);
    float wx = 1.f / (kap + fn);
    if (c == 0) {
        for (int d = threadIdx.x; d < DD; d += 256) mmu[d] = m[d];
    }
    for (int d = threadIdx.x; d < DD; d += 256) {
        float s = 0.f;
        for (int t = 0; t < cnt; ++t) s += Xs[(size_t)lidx[t] * DD + d];
        mmu[(size_t)(1 + c) * DD + d] = wm * m[d] + wx * s;
    }
}

// ---------------------------------------------------------------------------
// invert each 16x16 lower-triangular diagonal block of L
__global__ __launch_bounds__(64) void diag_inv16(const float* __restrict__ Lm,
                                                 float* __restrict__ Dinv) {
    int b = blockIdx.x;
    __shared__ float lt[PW][PW + 1];
    __shared__ float xt[PW][PW + 1];
    int tid = threadIdx.x;
    for (int t = tid; t < PW * PW; t += 64) {
        int i = t / PW, j = t % PW;
        lt[i][j] = Lm[(size_t)(b * PW + i) * DD + b * PW + j];
        xt[i][j] = 0.f;
    }
    __syncthreads();
    if (tid < PW) {
        int j = tid;
        xt[j][j] = 1.f / lt[j][j];
        for (int i = j + 1; i < PW; ++i) {
            float s = 0.f;
            for (int k = j; k < i; ++k) s += lt[i][k] * xt[k][j];
            xt[i][j] = -s / lt[i][i];
        }
    }
    __syncthreads();
    for (int t = tid; t < PW * PW; t += 64)
        Dinv[(size_t)b * PW * PW + t] = xt[t / PW][t % PW];
}

// ---------------------------------------------------------------------------
// column-panel TRTRI: one block per 16-wide column panel j. Walks row-blocks
// downward keeping the whole G panel in LDS.  G[r][j] = -Dinv_r * sum_{k=j}^{r-1} L[r][k] G[k][j]
__global__ __launch_bounds__(256) void trtri_panel(const float* __restrict__ Lm,
                                                   const float* __restrict__ Dinv,
                                                   float* __restrict__ G) {
    int j = blockIdx.x;
    __shared__ float Gpan[DD][PW];      // rows 16j.. stored from index 0 (48KB)
    __shared__ float Lc[PW][64 + 1];    // staged 16 x 64 L chunk
    __shared__ float Ssh[PW][PW + 1];
    int tid = threadIdx.x;

    // zero-fill upper sub-blocks within this column's 64-aligned diagonal tile
    // (the triangular GEMM reads the full 64x64 diagonal tile of G)
    int t64 = (j / 4) * 64;                    // start row of containing 64-tile
    int nz = j * PW - t64;                     // rows above diag block, within tile
    for (int t = tid; t < nz * PW; t += 256)
        G[(size_t)(t64 + t / PW) * DD + j * PW + t % PW] = 0.f;

    // diagonal block
    for (int t = tid; t < PW * PW; t += 256) {
        float v = Dinv[(size_t)j * PW * PW + t];
        Gpan[t / PW][t % PW] = v;
        G[(size_t)(j * PW + t / PW) * DD + j * PW + t % PW] = v;
    }
    __syncthreads();

    int a = tid >> 4, b = tid & 15;            // 16x16 thread tile
    for (int r = j + 1; r < NPB; ++r) {
        int K = (r - j) * PW;
        float s0 = 0.f, s1 = 0.f;
        for (int k0 = 0; k0 < K; k0 += 64) {
            int kw = K - k0 < 64 ? K - k0 : 64;
            for (int t = tid; t < PW * 64; t += 256) {
                int i = t >> 6, k = t & 63;
                Lc[i][k] = (k < kw) ? Lm[(size_t)(r * PW + i) * DD + j * PW + k0 + k] : 0.f;
            }
            __syncthreads();
#pragma unroll 4
            for (int k = 0; k < kw; k += 2) {
                s0 += Lc[a][k] * Gpan[k0 + k][b];
                s1 += Lc[a][k + 1] * Gpan[k0 + k + 1][b];
            }
            __syncthreads();
        }
        Ssh[a][b] = s0 + s1;
        __syncthreads();
        float v = 0.f;
        const float* Dr = Dinv + (size_t)r * PW * PW + a * PW;
        for (int k = 0; k <= a; ++k) v -= Dr[k] * Ssh[k][b];
        Gpan[(r - j) * PW + a][b] = v;
        G[(size_t)(r * PW + a) * DD + j * PW + b] = v;
        __syncthreads();
    }
}

// ---------------------------------------------------------------------------
// C[M][Nn] += A[M][K] * B[Nn][K]^T  via atomicAdd (C pre-zeroed).
// TRI: B lower triangular -> k <= column tile end. SPLIT: k-range split over blockIdx.z.
// SEL: A is the stacked [Qx(2048); Xs(1024); mmu(65)] selector.
template <bool TRI, int SPLIT, bool SEL>
__global__ __launch_bounds__(256) void gemm_nt(const float* __restrict__ A0,
                                               const float* __restrict__ A1,
                                               const float* __restrict__ A2,
                                               const float* __restrict__ B,
                                               float* __restrict__ Cc,
                                               int M, int Nn, int K) {
    __shared__ __align__(16) float As[32][68];
    __shared__ __align__(16) float Bs[32][68];
    int bm = blockIdx.x, bn = blockIdx.y, bz = blockIdx.z;
    int row0 = bm * 64, col0 = bn * 64;
    int tid = threadIdx.x;
    int tr = tid >> 4, tc = tid & 15;
    float acc[4][4] = {};
    int kmax = TRI ? ((bn + 1) * 64 < K ? (bn + 1) * 64 : K) : K;
    int nch = kmax >> 5;
    int klo = 32 * ((bz * nch) / SPLIT);
    int khi = 32 * (((bz + 1) * nch) / SPLIT);
    for (int k0 = klo; k0 < khi; k0 += 32) {
        for (int t = tid; t < 64 * 32; t += 256) {
            int r = t >> 5, kk = t & 31;
            int ar = row0 + r;
            float av = 0.f;
            if (ar < M) {
                const float* ap;
                if (SEL) {
                    if (ar < NQQ) ap = A0 + (size_t)ar * K;
                    else if (ar < NQQ + NSUP) ap = A1 + (size_t)(ar - NQQ) * K;
                    else ap = A2 + (size_t)(ar - NQQ - NSUP) * K;
                } else {
                    ap = A0 + (size_t)ar * K;
                }
                av = ap[k0 + kk];
            }
            As[kk][r] = av;
            int br = col0 + r;
            Bs[kk][r] = (br < Nn) ? B[(size_t)br * K + k0 + kk] : 0.f;
        }
        __syncthreads();
#pragma unroll
        for (int kk = 0; kk < 32; ++kk) {
            float4 av = *(const float4*)(&As[kk][tr << 2]);
            float4 bv = *(const float4*)(&Bs[kk][tc << 2]);
            float a[4] = {av.x, av.y, av.z, av.w};
            float b[4] = {bv.x, bv.y, bv.z, bv.w};
#pragma unroll
            for (int x = 0; x < 4; ++x)
#pragma unroll
                for (int y = 0; y < 4; ++y) acc[x][y] += a[x] * b[y];
        }
        __syncthreads();
    }
#pragma unroll
    for (int x = 0; x < 4; ++x) {
        int r = row0 + tr * 4 + x;
        if (r >= M) continue;
#pragma unroll
        for (int y = 0; y < 4; ++y) {
            int cc2 = col0 + tc * 4 + y;
            if (cc2 < Nn) atomicAdd(&Cc[(size_t)r * Nn + cc2], acc[x][y]);
        }
    }
}

// ---------------------------------------------------------------------------
// Vt row (c*18+i): i<16 -> TX[idx], i==16 -> sqrt(kap)*Tm, i==17 -> sqrt(kap+Nc)*Tmu_c
__global__ __launch_bounds__(256) void build_V(const float* __restrict__ Trows,
                                               const int* __restrict__ cls_idx,
                                               const int* __restrict__ cls_n,
                                               const float* __restrict__ kappa,
                                               float* __restrict__ Vt) {
    int row = blockIdx.x;
    int c = row / RR, i = row % RR;
    int cnt = cls_n[c];
    float kap = fabsf(kappa[0]) + 1e-6f;
    size_t srow;
    float sc = 1.f;
    if (i < SHOT) {
        if (i >= cnt) {
            for (int d = threadIdx.x; d < DD; d += 256) Vt[(size_t)row * DD + d] = 0.f;
            return;
        }
        srow = (size_t)NQQ + cls_idx[c * SHOT + i];
    } else if (i == SHOT) {
        srow = NQQ + NSUP;
        sc = sqrtf(kap);
    } else {
        srow = (size_t)NQQ + NSUP + 1 + c;
        sc = sqrtf(kap + (float)cnt);
    }
    for (int d = threadIdx.x; d < DD; d += 256)
        Vt[(size_t)row * DD + d] = sc * Trows[srow * DD + d];
}

// ---------------------------------------------------------------------------
// per class: M = J + Vt Vt^T (fp64), invert (GJ w/ pivoting, fp64), h, consts.
__global__ __launch_bounds__(256) void build_M(const float* __restrict__ Trows,
                                               const float* __restrict__ mmu,
                                               const float* __restrict__ Vt,
                                               const float* __restrict__ tdiag,
                                               const float* __restrict__ kappa,
                                               const float* __restrict__ nu,
                                               const int* __restrict__ cls_n,
                                               float* __restrict__ consts,
                                               float* __restrict__ hbuf,
                                               float* __restrict__ MinvO) {
    int c = blockIdx.x;
    __shared__ double Md[RR][RR];
    __shared__ double aug[RR][2 * RR];
    __shared__ double colk[RR];
    __shared__ double red[4];
    __shared__ double gj_logdet;
    __shared__ float hs[RR];
    __shared__ float ng2t_s, mu2_s;
    int tid = threadIdx.x;
    int wave = tid >> 6, lane = tid & 63;
    const float* Vc = Vt + (size_t)c * RR * DD;
    const float* Tmu = Trows + (size_t)(NQQ + NSUP + 1 + c) * DD;
    const float* mu_raw = mmu + (size_t)(1 + c) * DD;

    for (int p = wave; p < RR * RR + RR + 2; p += 4) {
        const float *va, *vb;
        if (p < RR * RR) {
            int i = p / RR, j = p % RR;
            if (i > j) continue;
            va = Vc + (size_t)i * DD; vb = Vc + (size_t)j * DD;
        } else if (p < RR * RR + RR) {
            va = Vc + (size_t)(p - RR * RR) * DD; vb = Tmu;
        } else if (p == RR * RR + RR) {
            va = Tmu; vb = Tmu;
        } else {
            va = mu_raw; vb = mu_raw;
        }
        double s = 0.0;
        for (int d = lane; d < DD; d += 64) s += (double)va[d] * (double)vb[d];
        for (int off = 32; off; off >>= 1) s += __shfl_down(s, off);
        if (lane == 0) {
            if (p < RR * RR) { int i = p / RR, j = p % RR; Md[i][j] = s; Md[j][i] = s; }
            else if (p < RR * RR + RR) hs[p - RR * RR] = (float)s;
            else if (p == RR * RR + RR) ng2t_s = (float)s;
            else mu2_s = (float)s;
        }
    }
    double sl = 0.0;
    for (int k = tid; k < DD; k += 256) sl += log((double)fabsf(tdiag[k]));
    for (int off = 32; off; off >>= 1) sl += __shfl_down(sl, off);
    if (lane == 0) red[wave] = sl;
    __syncthreads();

    if (tid == 0) {
        for (int i = 0; i < RR - 1; ++i) Md[i][i] += 1.0;
        Md[RR - 1][RR - 1] -= 1.0;
        gj_logdet = 0.0;
    }
    __syncthreads();
    for (int t = tid; t < RR * 2 * RR; t += 256) {
        int r2 = t / (2 * RR), j2 = t % (2 * RR);
        aug[r2][j2] = (j2 < RR) ? Md[r2][j2] : ((j2 - RR == r2) ? 1.0 : 0.0);
    }
    __syncthreads();
    for (int k = 0; k < RR; ++k) {
        if (tid == 0) {
            int piv = k; double best = fabs(aug[k][k]);
            for (int r2 = k + 1; r2 < RR; ++r2) {
                double v = fabs(aug[r2][k]);
                if (v > best) { best = v; piv = r2; }
            }
            if (piv != k) {
                for (int j2 = 0; j2 < 2 * RR; ++j2) {
                    double tmp = aug[k][j2]; aug[k][j2] = aug[piv][j2]; aug[piv][j2] = tmp;
                }
            }
            double pv = aug[k][k];
            gj_logdet += log(fabs(pv));
            double inv = 1.0 / pv;
            for (int j2 = 0; j2 < 2 * RR; ++j2) aug[k][j2] *= inv;
        }
        __syncthreads();
        if (tid < RR) colk[tid] = (tid == k) ? 0.0 : aug[tid][k];
        __syncthreads();
        for (int t = tid; t < RR * 2 * RR; t += 256) {
            int r2 = t / (2 * RR), j2 = t % (2 * RR);
            if (r2 != k) aug[r2][j2] -= colk[r2] * aug[k][j2];
        }
        __syncthreads();
    }
    if (tid == 0) {
        double sumlog = red[0] + red[1] + red[2] + red[3];
        double kap = fabs((double)kappa[0]) + 1e-6;
        double nu_ = fmax((double)nu[0], (double)(DD - 1) + 1e-6);
        double fn = (double)cls_n[c];
        double common = nu_ + fn + 1.0 - (double)DD;
        double scale = (kap + fn + 1.0) / (common * (kap + fn));
        double logdet_sigma = (double)DD * log(scale) + 2.0 * sumlog + gj_logdet;
        double bias = lgamma(0.5 * (common + DD)) - lgamma(0.5 * common)
                    - 0.5 * DD * log(common) - 0.5 * logdet_sigma;
        consts[c * 8 + 0] = (float)((1.0 - (double)REGP) / scale);
        consts[c * 8 + 1] = (float)common;
        consts[c * 8 + 2] = (float)(0.5 * (common + DD));
        consts[c * 8 + 3] = (float)bias;
        consts[c * 8 + 4] = (float)(1.0 / sqrt(kap + fn));
        consts[c * 8 + 5] = ng2t_s;
        consts[c * 8 + 6] = mu2_s;
        consts[c * 8 + 7] = 0.f;
    }
    __syncthreads();
    for (int t = tid; t < RR * RR; t += 256)
        MinvO[(size_t)c * RR * RR + t] = (float)aug[t / RR][RR + t % RR];
    if (tid < RR) hbuf[c * RR + tid] = hs[tid];
}

// ---------------------------------------------------------------------------
__global__ __launch_bounds__(256) void query_norms(const float* __restrict__ Qx,
                                                   const float* __restrict__ Trows,
                                                   float* __restrict__ q2,
                                                   float* __restrict__ nq2t) {
    int q = blockIdx.x * 4 + (threadIdx.x >> 6);
    int lane = threadIdx.x & 63;
    float s1 = 0.f, s2 = 0.f;
    for (int d = lane; d < DD; d += 64) {
        float a = Qx[(size_t)q * DD + d]; s1 += a * a;
        float b = Trows[(size_t)q * DD + d]; s2 += b * b;
    }
    for (int off = 32; off; off >>= 1) { s1 += __shfl_down(s1, off); s2 += __shfl_down(s2, off); }
    if (lane == 0) { q2[q] = s1; nq2t[q] = s2; }
}

// ---------------------------------------------------------------------------
__global__ __launch_bounds__(256) void final_kernel(const float* __restrict__ P,
                                                    const float* __restrict__ dotqmu,
                                                    const float* __restrict__ q2,
                                                    const float* __restrict__ nq2t,
                                                    const float* __restrict__ consts,
                                                    const float* __restrict__ hbuf,
                                                    const float* __restrict__ Minv,
                                                    float* __restrict__ out) {
    int c = blockIdx.x, qt = blockIdx.y;
    __shared__ float Ms[RR][RR];
    __shared__ float hlds[RR];
    __shared__ float cs[8];
    int tid = threadIdx.x;
    for (int t = tid; t < RR * RR; t += 256) Ms[t / RR][t % RR] = Minv[(size_t)c * RR * RR + t];
    if (tid < RR) hlds[tid] = hbuf[c * RR + tid];
    if (tid < 8) cs[tid] = consts[c * 8 + tid];
    __syncthreads();
    int q = qt * 256 + tid;
    const float* Pq = P + (size_t)q * (NC * RR) + c * RR;
    float p[RR];
    float p17raw = Pq[RR - 1];
#pragma unroll
    for (int i = 0; i < RR; ++i) p[i] = Pq[i] - hlds[i];
    float quad = 0.f;
#pragma unroll
    for (int i = 0; i < RR; ++i) {
        float t = 0.f;
#pragma unroll
        for (int j = 0; j < RR; ++j) t += Ms[i][j] * p[j];
        quad += p[i] * t;
    }
    float w1 = cs[0], common = cs[1], coef = cs[2], bias = cs[3];
    float inv_s17 = cs[4], ng2t = cs[5], mu2 = cs[6];
    float Gu2 = nq2t[q] - 2.f * p17raw * inv_s17 + ng2t;
    float u2 = q2[q] - 2.f * dotqmu[(size_t)q * NC + c] + mu2;
    float dist = w1 * (Gu2 - quad) + REGP * u2;
    out[(size_t)q * NC + c] = bias - coef * log1pf(dist / common);
}

// ---------------------------------------------------------------------------
extern "C" void kernel_launch(void* const* d_in, const int* in_sizes, int n_in,
                              void* d_out, int out_size, void* d_ws, size_t ws_size,
                              hipStream_t stream) {
    const float* Xs    = (const float*)d_in[0];
    const float* Qx    = (const float*)d_in[1];
    const float* m     = (const float*)d_in[2];
    const float* kappa = (const float*)d_in[3];
    const float* nu    = (const float*)d_in[4];
    const float* tdiag = (const float*)d_in[5];
    const float* tlow  = (const float*)d_in[6];
    const int* labels  = (const int*)d_in[7];
    float* out = (float*)d_out;

    float* ws = (float*)d_ws;
    float* Lm     = ws;                                  // D*D
    float* G      = Lm + DDS;                            // D*D
    float* mmu    = G + DDS;                             // (NC+1)*D  [m; mu_0..63]
    float* Dinv   = mmu + (size_t)(NC + 1) * DD;         // NPB*PW*PW
    float* Trows  = Dinv + (size_t)NPB * PW * PW;        // NROWS*D   [TQ; TX; Tm; Tmu]
    float* Vt     = Trows + (size_t)NROWS * DD;          // NC*RR*D
    float* P      = Vt + (size_t)NC * RR * DD;           // NQ*NC*RR
    float* dotqmu = P + (size_t)NQQ * NC * RR;           // NQ*NC   (contiguous after P)
    float* q2     = dotqmu + (size_t)NQQ * NC;           // NQ
    float* nq2t   = q2 + NQQ;                            // NQ
    float* consts = nq2t + NQQ;                          // NC*8
    float* hbuf   = consts + NC * 8;                     // NC*RR
    float* MinvB  = hbuf + NC * RR;                      // NC*RR*RR
    int* cls_idx  = (int*)(MinvB + (size_t)NC * RR * RR);// NC*SHOT
    int* cls_n    = cls_idx + NC * SHOT;                 // NC

    // zero the atomic-accumulated buffers (Trows; P+dotqmu contiguous)
    hipMemsetAsync(Trows, 0, (size_t)NROWS * DD * sizeof(float), stream);
    hipMemsetAsync(P, 0, ((size_t)NQQ * NC * RR + (size_t)NQQ * NC) * sizeof(float), stream);

    build_L<<<(DDS + 255) / 256, 256, 0, stream>>>(tdiag, tlow, Lm);
    class_stats<<<NC, 256, 0, stream>>>(Xs, m, labels, kappa, mmu, cls_idx, cls_n);
    diag_inv16<<<NPB, 64, 0, stream>>>(Lm, Dinv);
    trtri_panel<<<NPB, 256, 0, stream>>>(Lm, Dinv, G);
    // transformed rows: stacked [Qx; Xs; mmu] @ G^T (G lower triangular), split-K=2
    gemm_nt<true, 2, true><<<dim3((NROWS + 63) / 64, DD / 64, 2), 256, 0, stream>>>(
        Qx, Xs, mmu, G, Trows, NROWS, DD, DD);
    build_V<<<NC * RR, 256, 0, stream>>>(Trows, cls_idx, cls_n, kappa, Vt);
    build_M<<<NC, 256, 0, stream>>>(Trows, mmu, Vt, tdiag, kappa, nu, cls_n, consts, hbuf, MinvB);
    query_norms<<<NQQ / 4, 256, 0, stream>>>(Qx, Trows, q2, nq2t);
    gemm_nt<false, 2, false><<<dim3(NQQ / 64, (NC * RR) / 64, 2), 256, 0, stream>>>(
        Trows, nullptr, nullptr, Vt, P, NQQ, NC * RR, DD);
    gemm_nt<false, 4, false><<<dim3(NQQ / 64, 1, 4), 256, 0, stream>>>(
        Qx, nullptr, nullptr, mmu + DD, dotqmu, NQQ, NC, DD);
    final_kernel<<<dim3(NC, NQQ / 256), 256, 0, stream>>>(P, dotqmu, q2, nq2t, consts, hbuf, MinvB, out);
}

// Round 9
// 842.572 us; speedup vs baseline: 1.6055x; 1.1262x over previous
//
#include <hip/hip_runtime.h>
#include <hip/hip_bf16.h>
#include <math.h>

// ---- problem constants (match reference setup) ----
constexpr int DD   = 768;    // feature dim
constexpr int NSUP = 1024;   // support rows (WAY*SHOT)
constexpr int NQQ  = 2048;   // queries
constexpr int NC   = 64;     // classes (way)
constexpr int SHOT = 16;
constexpr int RR   = 18;     // Woodbury rank = SHOT + 2
constexpr float REGP = 0.5f;
constexpr int DDS = DD * DD;
constexpr int NROWS = NQQ + NSUP + 1 + NC; // stacked transformed rows: [TQ; TX; Tm; Tmu]
constexpr int TRB  = 16;     // RHS rows per TRSM block
constexpr int NTB  = (NROWS + TRB - 1) / TRB; // 197 trsm blocks
constexpr int NDB  = DD / 64; // 12 diagonal 64-blocks

// ---------------------------------------------------------------------------
// L = diag(|triu_diag|) + strictly-lower(triu_lower)
__global__ __launch_bounds__(256) void build_L(const float* __restrict__ tdiag,
                                               const float* __restrict__ tlow,
                                               float* __restrict__ Lm) {
    int idx = blockIdx.x * 256 + threadIdx.x;
    if (idx >= DDS) return;
    int i = idx / DD, j = idx % DD;
    float v = (i == j) ? fabsf(tdiag[i]) : (i > j ? tlow[idx] : 0.f);
    Lm[idx] = v;
}

// ---------------------------------------------------------------------------
// per-class: gather indices, compute mu_c into mmu rows 1..64; block0 copies m to row 0
__global__ __launch_bounds__(256) void class_stats(const float* __restrict__ Xs,
                                                   const float* __restrict__ m,
                                                   const int* __restrict__ labels,
                                                   const float* __restrict__ kappa,
                                                   float* __restrict__ mmu,
                                                   int* __restrict__ cls_idx,
                                                   int* __restrict__ cls_n) {
    int c = blockIdx.x;
    __shared__ int lidx[SHOT];
    __shared__ int lcount;
    if (threadIdx.x == 0) lcount = 0;
    __syncthreads();
    for (int n = threadIdx.x; n < NSUP; n += 256) {
        if (labels[n] == c) {
            int pos = atomicAdd(&lcount, 1);
            if (pos < SHOT) lidx[pos] = n;
        }
    }
    __syncthreads();
    int cnt = lcount < SHOT ? lcount : SHOT;
    if (threadIdx.x < SHOT) cls_idx[c * SHOT + threadIdx.x] = (threadIdx.x < cnt) ? lidx[threadIdx.x] : 0;
    if (threadIdx.x == 0) cls_n[c] = cnt;
    float kap = fabsf(kappa[0]) + 1e-6f;
    float fn = (float)cnt;
    float wm = kap / (kap + fn);
    float wx = 1.f / (kap + fn);
    if (c == 0) {
        for (int d = threadIdx.x; d < DD; d += 256) mmu[d] = m[d];
    }
    for (int d = threadIdx.x; d < DD; d += 256) {
        float s = 0.f;
        for (int t = 0; t < cnt; ++t) s += Xs[(size_t)lidx[t] * DD + d];
        mmu[(size_t)(1 + c) * DD + d] = wm * m[d] + wx * s;
    }
}

// ---------------------------------------------------------------------------
// invert each 64x64 lower-triangular diagonal block of L.
// Output TRANSPOSED for coalesced TRSM reads: DinvT[b][m][a] = (L_bb^{-1})[a][m]
__global__ __launch_bounds__(64) void diag_inv64(const float* __restrict__ Lm,
                                                 float* __restrict__ DinvT) {
    int b = blockIdx.x;
    __shared__ float lt[64][65];
    __shared__ float xt[64][65];
    int tid = threadIdx.x; // 64 threads
    for (int i = 0; i < 64; ++i) {
        lt[i][tid] = Lm[(size_t)(b * 64 + i) * DD + b * 64 + tid];
        xt[i][tid] = 0.f;
    }
    __syncthreads();
    int j = tid; // column j, independent per thread
    xt[j][j] = 1.f / lt[j][j];
    for (int i = j + 1; i < 64; ++i) {
        float s = 0.f;
        for (int k = j; k < i; ++k) s += lt[i][k] * xt[k][j];
        xt[i][j] = -s / lt[i][i];
    }
    __syncthreads();
    // DinvT[b*4096 + m*64 + a] = xt[a][m]
    for (int t = tid; t < 4096; t += 64)
        DinvT[(size_t)b * 4096 + t] = xt[t & 63][t >> 6];
}

// ---------------------------------------------------------------------------
// Fused TRSM: Trows[q] = row q of (A @ G^T)  via forward substitution
//   L y = a  solved block-wise: y_r = Dinv_r (a_r - sum_{k<r} L[r,k] y_k)
// One block owns TRB=16 RHS rows; Y panel lives in LDS; 12 sequential row-block
// steps, each a [64 x 16] GEMM update chunked over K.
// A is the stacked selector [Qx(2048); Xs(1024); mmu(65)].
__global__ __launch_bounds__(256) void trsm_kernel(const float* __restrict__ Qx,
                                                   const float* __restrict__ Xs,
                                                   const float* __restrict__ mmu,
                                                   const float* __restrict__ Lm,
                                                   const float* __restrict__ DinvT,
                                                   float* __restrict__ Trows) {
    __shared__ float Ylds[DD][TRB];   // 48 KB: solution panel
    __shared__ float Lc[64][33];      // 8.4 KB: staged 64x32 L chunk (padded)
    __shared__ float Ssh[64][TRB];    // 4 KB: T = x_r - S
    int tid = threadIdx.x;
    int a = tid & 63;                 // row within 64-block (lane)
    int g = tid >> 6;                 // rhs group (wave id), 4 rhs per group
    int q0 = blockIdx.x * TRB;

    // resolve this thread's 4 RHS row pointers (stacked selector)
    const float* xp[4];
    bool valid[4];
#pragma unroll
    for (int j = 0; j < 4; ++j) {
        int q = q0 + g * 4 + j;
        valid[j] = q < NROWS;
        int qq = valid[j] ? q : 0;
        if (qq < NQQ) xp[j] = Qx + (size_t)qq * DD;
        else if (qq < NQQ + NSUP) xp[j] = Xs + (size_t)(qq - NQQ) * DD;
        else xp[j] = mmu + (size_t)(qq - NQQ - NSUP) * DD;
    }

    for (int r = 0; r < NDB; ++r) {
        int r0 = r * 64;
        float s0 = 0.f, s1 = 0.f, s2 = 0.f, s3 = 0.f;
        // S[a][g4+j] = sum_{k<r0} L[r0+a][k] * Y[k][g4+j], chunked by 32
        for (int k0 = 0; k0 < r0; k0 += 32) {
            for (int t = tid; t < 64 * 32; t += 256) {
                int i = t >> 5, k = t & 31;
                Lc[i][k] = Lm[(size_t)(r0 + i) * DD + k0 + k];
            }
            __syncthreads();
#pragma unroll
            for (int kk = 0; kk < 32; ++kk) {
                float lv = Lc[a][kk];
                const float* yr = &Ylds[k0 + kk][g * 4]; // wave-uniform broadcast
                s0 += lv * yr[0]; s1 += lv * yr[1];
                s2 += lv * yr[2]; s3 += lv * yr[3];
            }
            __syncthreads();
        }
        // T[a][j] = x_j[r0+a] - S  (coalesced: 64 consecutive d per (g,j))
        Ssh[a][g * 4 + 0] = (valid[0] ? xp[0][r0 + a] : 0.f) - s0;
        Ssh[a][g * 4 + 1] = (valid[1] ? xp[1][r0 + a] : 0.f) - s1;
        Ssh[a][g * 4 + 2] = (valid[2] ? xp[2][r0 + a] : 0.f) - s2;
        Ssh[a][g * 4 + 3] = (valid[3] ? xp[3][r0 + a] : 0.f) - s3;
        __syncthreads();
        // y_r[a][j] = sum_m Dinv_r[a][m] * T[m][j];  Dinv_r[a][m] = DinvT[r][m*64+a]
        float o0 = 0.f, o1 = 0.f, o2 = 0.f, o3 = 0.f;
        const float* dptr = DinvT + (size_t)r * 4096 + a;
#pragma unroll 8
        for (int m = 0; m < 64; ++m) {
            float dv = dptr[m * 64];                  // 256B coalesced across lanes
            const float* tr = &Ssh[m][g * 4];         // wave-uniform broadcast
            o0 += dv * tr[0]; o1 += dv * tr[1];
            o2 += dv * tr[2]; o3 += dv * tr[3];
        }
        __syncthreads();   // all Ssh reads done before anyone rewrites next step
        Ylds[r0 + a][g * 4 + 0] = o0;
        Ylds[r0 + a][g * 4 + 1] = o1;
        Ylds[r0 + a][g * 4 + 2] = o2;
        Ylds[r0 + a][g * 4 + 3] = o3;
        // global store (coalesced: 64 consecutive d per (g,j))
#pragma unroll
        for (int j = 0; j < 4; ++j) {
            int q = q0 + g * 4 + j;
            float ov = (j == 0) ? o0 : (j == 1) ? o1 : (j == 2) ? o2 : o3;
            if (q < NROWS) Trows[(size_t)q * DD + r0 + a] = ov;
        }
        __syncthreads();   // Ylds rows r0.. visible before next step's MAC reads
    }
}

// ---------------------------------------------------------------------------
// C[M][Nn] += A[M][K] * B[Nn][K]^T  via atomicAdd (C pre-zeroed).
// SPLIT: k-range split over blockIdx.z.
template <int SPLIT>
__global__ __launch_bounds__(256) void gemm_nt(const float* __restrict__ A0,
                                               const float* __restrict__ B,
                                               float* __restrict__ Cc,
                                               int M, int Nn, int K) {
    __shared__ __align__(16) float As[32][68];
    __shared__ __align__(16) float Bs[32][68];
    int bm = blockIdx.x, bn = blockIdx.y, bz = blockIdx.z;
    int row0 = bm * 64, col0 = bn * 64;
    int tid = threadIdx.x;
    int tr = tid >> 4, tc = tid & 15;
    float acc[4][4] = {};
    int nch = K >> 5;
    int klo = 32 * ((bz * nch) / SPLIT);
    int khi = 32 * (((bz + 1) * nch) / SPLIT);
    for (int k0 = klo; k0 < khi; k0 += 32) {
        for (int t = tid; t < 64 * 32; t += 256) {
            int r = t >> 5, kk = t & 31;
            int ar = row0 + r;
            As[kk][r] = (ar < M) ? A0[(size_t)ar * K + k0 + kk] : 0.f;
            int br = col0 + r;
            Bs[kk][r] = (br < Nn) ? B[(size_t)br * K + k0 + kk] : 0.f;
        }
        __syncthreads();
#pragma unroll
        for (int kk = 0; kk < 32; ++kk) {
            float4 av = *(const float4*)(&As[kk][tr << 2]);
            float4 bv = *(const float4*)(&Bs[kk][tc << 2]);
            float a[4] = {av.x, av.y, av.z, av.w};
            float b[4] = {bv.x, bv.y, bv.z, bv.w};
#pragma unroll
            for (int x = 0; x < 4; ++x)
#pragma unroll
                for (int y = 0; y < 4; ++y) acc[x][y] += a[x] * b[y];
        }
        __syncthreads();
    }
#pragma unroll
    for (int x = 0; x < 4; ++x) {
        int r = row0 + tr * 4 + x;
        if (r >= M) continue;
#pragma unroll
        for (int y = 0; y < 4; ++y) {
            int cc2 = col0 + tc * 4 + y;
            if (cc2 < Nn) atomicAdd(&Cc[(size_t)r * Nn + cc2], acc[x][y]);
        }
    }
}

// ---------------------------------------------------------------------------
// Vt row (c*18+i): i<16 -> TX[idx], i==16 -> sqrt(kap)*Tm, i==17 -> sqrt(kap+Nc)*Tmu_c
__global__ __launch_bounds__(256) void build_V(const float* __restrict__ Trows,
                                               const int* __restrict__ cls_idx,
                                               const int* __restrict__ cls_n,
                                               const float* __restrict__ kappa,
                                               float* __restrict__ Vt) {
    int row = blockIdx.x;
    int c = row / RR, i = row % RR;
    int cnt = cls_n[c];
    float kap = fabsf(kappa[0]) + 1e-6f;
    size_t srow;
    float sc = 1.f;
    if (i < SHOT) {
        if (i >= cnt) {
            for (int d = threadIdx.x; d < DD; d += 256) Vt[(size_t)row * DD + d] = 0.f;
            return;
        }
        srow = (size_t)NQQ + cls_idx[c * SHOT + i];
    } else if (i == SHOT) {
        srow = NQQ + NSUP;
        sc = sqrtf(kap);
    } else {
        srow = (size_t)NQQ + NSUP + 1 + c;
        sc = sqrtf(kap + (float)cnt);
    }
    for (int d = threadIdx.x; d < DD; d += 256)
        Vt[(size_t)row * DD + d] = sc * Trows[srow * DD + d];
}

// ---------------------------------------------------------------------------
// per class: M = J + Vt Vt^T (fp64), invert (GJ w/ pivoting, fp64), h, consts.
__global__ __launch_bounds__(256) void build_M(const float* __restrict__ Trows,
                                               const float* __restrict__ mmu,
                                               const float* __restrict__ Vt,
                                               const float* __restrict__ tdiag,
                                               const float* __restrict__ kappa,
                                               const float* __restrict__ nu,
                                               const int* __restrict__ cls_n,
                                               float* __restrict__ consts,
                                               float* __restrict__ hbuf,
                                               float* __restrict__ MinvO) {
    int c = blockIdx.x;
    __shared__ double Md[RR][RR];
    __shared__ double aug[RR][2 * RR];
    __shared__ double colk[RR];
    __shared__ double red[4];
    __shared__ double gj_logdet;
    __shared__ float hs[RR];
    __shared__ float ng2t_s, mu2_s;
    int tid = threadIdx.x;
    int wave = tid >> 6, lane = tid & 63;
    const float* Vc = Vt + (size_t)c * RR * DD;
    const float* Tmu = Trows + (size_t)(NQQ + NSUP + 1 + c) * DD;
    const float* mu_raw = mmu + (size_t)(1 + c) * DD;

    for (int p = wave; p < RR * RR + RR + 2; p += 4) {
        const float *va, *vb;
        if (p < RR * RR) {
            int i = p / RR, j = p % RR;
            if (i > j) continue;
            va = Vc + (size_t)i * DD; vb = Vc + (size_t)j * DD;
        } else if (p < RR * RR + RR) {
            va = Vc + (size_t)(p - RR * RR) * DD; vb = Tmu;
        } else if (p == RR * RR + RR) {
            va = Tmu; vb = Tmu;
        } else {
            va = mu_raw; vb = mu_raw;
        }
        double s = 0.0;
        for (int d = lane; d < DD; d += 64) s += (double)va[d] * (double)vb[d];
        for (int off = 32; off; off >>= 1) s += __shfl_down(s, off);
        if (lane == 0) {
            if (p < RR * RR) { int i = p / RR, j = p % RR; Md[i][j] = s; Md[j][i] = s; }
            else if (p < RR * RR + RR) hs[p - RR * RR] = (float)s;
            else if (p == RR * RR + RR) ng2t_s = (float)s;
            else mu2_s = (float)s;
        }
    }
    double sl = 0.0;
    for (int k = tid; k < DD; k += 256) sl += log((double)fabsf(tdiag[k]));
    for (int off = 32; off; off >>= 1) sl += __shfl_down(sl, off);
    if (lane == 0) red[wave] = sl;
    __syncthreads();

    if (tid == 0) {
        for (int i = 0; i < RR - 1; ++i) Md[i][i] += 1.0;
        Md[RR - 1][RR - 1] -= 1.0;
        gj_logdet = 0.0;
    }
    __syncthreads();
    for (int t = tid; t < RR * 2 * RR; t += 256) {
        int r2 = t / (2 * RR), j2 = t % (2 * RR);
        aug[r2][j2] = (j2 < RR) ? Md[r2][j2] : ((j2 - RR == r2) ? 1.0 : 0.0);
    }
    __syncthreads();
    for (int k = 0; k < RR; ++k) {
        if (tid == 0) {
            int piv = k; double best = fabs(aug[k][k]);
            for (int r2 = k + 1; r2 < RR; ++r2) {
                double v = fabs(aug[r2][k]);
                if (v > best) { best = v; piv = r2; }
            }
            if (piv != k) {
                for (int j2 = 0; j2 < 2 * RR; ++j2) {
                    double tmp = aug[k][j2]; aug[k][j2] = aug[piv][j2]; aug[piv][j2] = tmp;
                }
            }
            double pv = aug[k][k];
            gj_logdet += log(fabs(pv));
            double inv = 1.0 / pv;
            for (int j2 = 0; j2 < 2 * RR; ++j2) aug[k][j2] *= inv;
        }
        __syncthreads();
        if (tid < RR) colk[tid] = (tid == k) ? 0.0 : aug[tid][k];
        __syncthreads();
        for (int t = tid; t < RR * 2 * RR; t += 256) {
            int r2 = t / (2 * RR), j2 = t % (2 * RR);
            if (r2 != k) aug[r2][j2] -= colk[r2] * aug[k][j2];
        }
        __syncthreads();
    }
    if (tid == 0) {
        double sumlog = red[0] + red[1] + red[2] + red[3];
        double kap = fabs((double)kappa[0]) + 1e-6;
        double nu_ = fmax((double)nu[0], (double)(DD - 1) + 1e-6);
        double fn = (double)cls_n[c];
        double common = nu_ + fn + 1.0 - (double)DD;
        double scale = (kap + fn + 1.0) / (common * (kap + fn));
        double logdet_sigma = (double)DD * log(scale) + 2.0 * sumlog + gj_logdet;
        double bias = lgamma(0.5 * (common + DD)) - lgamma(0.5 * common)
                    - 0.5 * DD * log(common) - 0.5 * logdet_sigma;
        consts[c * 8 + 0] = (float)((1.0 - (double)REGP) / scale);
        consts[c * 8 + 1] = (float)common;
        consts[c * 8 + 2] = (float)(0.5 * (common + DD));
        consts[c * 8 + 3] = (float)bias;
        consts[c * 8 + 4] = (float)(1.0 / sqrt(kap + fn));
        consts[c * 8 + 5] = ng2t_s;
        consts[c * 8 + 6] = mu2_s;
        consts[c * 8 + 7] = 0.f;
    }
    __syncthreads();
    for (int t = tid; t < RR * RR; t += 256)
        MinvO[(size_t)c * RR * RR + t] = (float)aug[t / RR][RR + t % RR];
    if (tid < RR) hbuf[c * RR + tid] = hs[tid];
}

// ---------------------------------------------------------------------------
__global__ __launch_bounds__(256) void query_norms(const float* __restrict__ Qx,
                                                   const float* __restrict__ Trows,
                                                   float* __restrict__ q2,
                                                   float* __restrict__ nq2t) {
    int q = blockIdx.x * 4 + (threadIdx.x >> 6);
    int lane = threadIdx.x & 63;
    float s1 = 0.f, s2 = 0.f;
    for (int d = lane; d < DD; d += 64) {
        float a = Qx[(size_t)q * DD + d]; s1 += a * a;
        float b = Trows[(size_t)q * DD + d]; s2 += b * b;
    }
    for (int off = 32; off; off >>= 1) { s1 += __shfl_down(s1, off); s2 += __shfl_down(s2, off); }
    if (lane == 0) { q2[q] = s1; nq2t[q] = s2; }
}

// ---------------------------------------------------------------------------
__global__ __launch_bounds__(256) void final_kernel(const float* __restrict__ P,
                                                    const float* __restrict__ dotqmu,
                                                    const float* __restrict__ q2,
                                                    const float* __restrict__ nq2t,
                                                    const float* __restrict__ consts,
                                                    const float* __restrict__ hbuf,
                                                    const float* __restrict__ Minv,
                                                    float* __restrict__ out) {
    int c = blockIdx.x, qt = blockIdx.y;
    __shared__ float Ms[RR][RR];
    __shared__ float hlds[RR];
    __shared__ float cs[8];
    int tid = threadIdx.x;
    for (int t = tid; t < RR * RR; t += 256) Ms[t / RR][t % RR] = Minv[(size_t)c * RR * RR + t];
    if (tid < RR) hlds[tid] = hbuf[c * RR + tid];
    if (tid < 8) cs[tid] = consts[c * 8 + tid];
    __syncthreads();
    int q = qt * 256 + tid;
    const float* Pq = P + (size_t)q * (NC * RR) + c * RR;
    float p[RR];
    float p17raw = Pq[RR - 1];
#pragma unroll
    for (int i = 0; i < RR; ++i) p[i] = Pq[i] - hlds[i];
    float quad = 0.f;
#pragma unroll
    for (int i = 0; i < RR; ++i) {
        float t = 0.f;
#pragma unroll
        for (int j = 0; j < RR; ++j) t += Ms[i][j] * p[j];
        quad += p[i] * t;
    }
    float w1 = cs[0], common = cs[1], coef = cs[2], bias = cs[3];
    float inv_s17 = cs[4], ng2t = cs[5], mu2 = cs[6];
    float Gu2 = nq2t[q] - 2.f * p17raw * inv_s17 + ng2t;
    float u2 = q2[q] - 2.f * dotqmu[(size_t)q * NC + c] + mu2;
    float dist = w1 * (Gu2 - quad) + REGP * u2;
    out[(size_t)q * NC + c] = bias - coef * log1pf(dist / common);
}

// ---------------------------------------------------------------------------
extern "C" void kernel_launch(void* const* d_in, const int* in_sizes, int n_in,
                              void* d_out, int out_size, void* d_ws, size_t ws_size,
                              hipStream_t stream) {
    const float* Xs    = (const float*)d_in[0];
    const float* Qx    = (const float*)d_in[1];
    const float* m     = (const float*)d_in[2];
    const float* kappa = (const float*)d_in[3];
    const float* nu    = (const float*)d_in[4];
    const float* tdiag = (const float*)d_in[5];
    const float* tlow  = (const float*)d_in[6];
    const int* labels  = (const int*)d_in[7];
    float* out = (float*)d_out;

    float* ws = (float*)d_ws;
    float* Lm     = ws;                                  // D*D
    float* mmu    = Lm + DDS;                            // (NC+1)*D  [m; mu_0..63]
    float* DinvT  = mmu + (size_t)(NC + 1) * DD;         // 12*64*64 (transposed diag inverses)
    float* Trows  = DinvT + (size_t)NDB * 64 * 64;       // NROWS*D   [TQ; TX; Tm; Tmu]
    float* Vt     = Trows + (size_t)NROWS * DD;          // NC*RR*D
    float* P      = Vt + (size_t)NC * RR * DD;           // NQ*NC*RR
    float* dotqmu = P + (size_t)NQQ * NC * RR;           // NQ*NC   (contiguous after P)
    float* q2     = dotqmu + (size_t)NQQ * NC;           // NQ
    float* nq2t   = q2 + NQQ;                            // NQ
    float* consts = nq2t + NQQ;                          // NC*8
    float* hbuf   = consts + NC * 8;                     // NC*RR
    float* MinvB  = hbuf + NC * RR;                      // NC*RR*RR
    int* cls_idx  = (int*)(MinvB + (size_t)NC * RR * RR);// NC*SHOT
    int* cls_n    = cls_idx + NC * SHOT;                 // NC

    // zero only the atomic-accumulated buffers (P + dotqmu contiguous)
    hipMemsetAsync(P, 0, ((size_t)NQQ * NC * RR + (size_t)NQQ * NC) * sizeof(float), stream);

    build_L<<<(DDS + 255) / 256, 256, 0, stream>>>(tdiag, tlow, Lm);
    class_stats<<<NC, 256, 0, stream>>>(Xs, m, labels, kappa, mmu, cls_idx, cls_n);
    diag_inv64<<<NDB, 64, 0, stream>>>(Lm, DinvT);
    // fused TRSM replaces explicit TRTRI + transform GEMM:
    trsm_kernel<<<NTB, 256, 0, stream>>>(Qx, Xs, mmu, Lm, DinvT, Trows);
    build_V<<<NC * RR, 256, 0, stream>>>(Trows, cls_idx, cls_n, kappa, Vt);
    build_M<<<NC, 256, 0, stream>>>(Trows, mmu, Vt, tdiag, kappa, nu, cls_n, consts, hbuf, MinvB);
    query_norms<<<NQQ / 4, 256, 0, stream>>>(Qx, Trows, q2, nq2t);
    gemm_nt<2><<<dim3(NQQ / 64, (NC * RR) / 64, 2), 256, 0, stream>>>(
        Trows, Vt, P, NQQ, NC * RR, DD);
    gemm_nt<4><<<dim3(NQQ / 64, 1, 4), 256, 0, stream>>>(
        Qx, mmu + DD, dotqmu, NQQ, NC, DD);
    final_kernel<<<dim3(NC, NQQ / 256), 256, 0, stream>>>(P, dotqmu, q2, nq2t, consts, hbuf, MinvB, out);
}

// Round 10
// 647.681 us; speedup vs baseline: 2.0885x; 1.3009x over previous
//
#include <hip/hip_runtime.h>
#include <hip/hip_bf16.h>
#include <math.h>

// ---- problem constants (match reference setup) ----
constexpr int DD   = 768;    // feature dim
constexpr int NSUP = 1024;   // support rows (WAY*SHOT)
constexpr int NQQ  = 2048;   // queries
constexpr int NC   = 64;     // classes (way)
constexpr int SHOT = 16;
constexpr int RR   = 18;     // Woodbury rank = SHOT + 2
constexpr float REGP = 0.5f;
constexpr int DDS = DD * DD;
constexpr int NROWS = NQQ + NSUP + 1 + NC; // stacked rows: [Q; X; m; mu] -> transformed in place
constexpr int TRB  = 16;     // RHS rows per TRSM block
constexpr int NTB  = (NROWS + TRB - 1) / TRB; // 197 trsm blocks
constexpr int NDB  = DD / 64; // 12 diagonal 64-blocks
constexpr int LW   = 384;    // TRSM leaf width
constexpr int LB   = LW / 64;// 6 leaf 64-blocks

// ---------------------------------------------------------------------------
// L = diag(|triu_diag|) + strictly-lower(triu_lower)
__global__ __launch_bounds__(256) void build_L(const float* __restrict__ tdiag,
                                               const float* __restrict__ tlow,
                                               float* __restrict__ Lm) {
    int idx = blockIdx.x * 256 + threadIdx.x;
    if (idx >= DDS) return;
    int i = idx / DD, j = idx % DD;
    float v = (i == j) ? fabsf(tdiag[i]) : (i > j ? tlow[idx] : 0.f);
    Lm[idx] = v;
}

// ---------------------------------------------------------------------------
// per-class: gather indices, compute mu_c into mmu rows 1..64; block0 copies m to row 0
__global__ __launch_bounds__(256) void class_stats(const float* __restrict__ Xs,
                                                   const float* __restrict__ m,
                                                   const int* __restrict__ labels,
                                                   const float* __restrict__ kappa,
                                                   float* __restrict__ mmu,
                                                   int* __restrict__ cls_idx,
                                                   int* __restrict__ cls_n) {
    int c = blockIdx.x;
    __shared__ int lidx[SHOT];
    __shared__ int lcount;
    if (threadIdx.x == 0) lcount = 0;
    __syncthreads();
    for (int n = threadIdx.x; n < NSUP; n += 256) {
        if (labels[n] == c) {
            int pos = atomicAdd(&lcount, 1);
            if (pos < SHOT) lidx[pos] = n;
        }
    }
    __syncthreads();
    int cnt = lcount < SHOT ? lcount : SHOT;
    if (threadIdx.x < SHOT) cls_idx[c * SHOT + threadIdx.x] = (threadIdx.x < cnt) ? lidx[threadIdx.x] : 0;
    if (threadIdx.x == 0) cls_n[c] = cnt;
    float kap = fabsf(kappa[0]) + 1e-6f;
    float fn = (float)cnt;
    float wm = kap / (kap + fn);
    float wx = 1.f / (kap + fn);
    if (c == 0) {
        for (int d = threadIdx.x; d < DD; d += 256) mmu[d] = m[d];
    }
    for (int d = threadIdx.x; d < DD; d += 256) {
        float s = 0.f;
        for (int t = 0; t < cnt; ++t) s += Xs[(size_t)lidx[t] * DD + d];
        mmu[(size_t)(1 + c) * DD + d] = wm * m[d] + wx * s;
    }
}

// ---------------------------------------------------------------------------
// invert each 64x64 lower-triangular diagonal block of L.
// Output TRANSPOSED for coalesced TRSM reads: DinvT[b][m][a] = (L_bb^{-1})[a][m]
__global__ __launch_bounds__(64) void diag_inv64(const float* __restrict__ Lm,
                                                 float* __restrict__ DinvT) {
    int b = blockIdx.x;
    __shared__ float lt[64][65];
    __shared__ float xt[64][65];
    int tid = threadIdx.x; // 64 threads
    for (int i = 0; i < 64; ++i) {
        lt[i][tid] = Lm[(size_t)(b * 64 + i) * DD + b * 64 + tid];
        xt[i][tid] = 0.f;
    }
    __syncthreads();
    int j = tid; // column j, independent per thread
    xt[j][j] = 1.f / lt[j][j];
    for (int i = j + 1; i < 64; ++i) {
        float s = 0.f;
        for (int k = j; k < i; ++k) s += lt[i][k] * xt[k][j];
        xt[i][j] = -s / lt[i][i];
    }
    __syncthreads();
    // DinvT[b*4096 + m*64 + a] = xt[a][m]
    for (int t = tid; t < 4096; t += 64)
        DinvT[(size_t)b * 4096 + t] = xt[t & 63][t >> 6];
}

// ---------------------------------------------------------------------------
// copy stacked [Qx; Xs; mmu] into Trows (float4), so TRSM can solve in place
__global__ __launch_bounds__(256) void copy_stack(const float* __restrict__ Qx,
                                                  const float* __restrict__ Xs,
                                                  const float* __restrict__ mmu,
                                                  float* __restrict__ Trows) {
    int f = blockIdx.x * 256 + threadIdx.x;       // float4 index
    if (f >= NROWS * (DD / 4)) return;
    int q = f / (DD / 4);
    int d4 = f % (DD / 4);
    const float* src;
    if (q < NQQ) src = Qx + (size_t)q * DD;
    else if (q < NQQ + NSUP) src = Xs + (size_t)(q - NQQ) * DD;
    else src = mmu + (size_t)(q - NQQ - NSUP) * DD;
    float4 v = *(const float4*)(src + d4 * 4);
    *(float4*)(Trows + (size_t)q * DD + d4 * 4) = v;
}

// ---------------------------------------------------------------------------
// Leaf TRSM over columns [c0, c0+LW): forward substitution in place on Trows.
// One block owns TRB=16 rows; leaf Y panel in LDS; LB=6 steps, 64-wide chunks.
__global__ __launch_bounds__(256) void leaf_trsm(float* __restrict__ Trows,
                                                 const float* __restrict__ Lm,
                                                 const float* __restrict__ DinvT,
                                                 int c0) {
    __shared__ float Ylds[LW * 17];   // 26.1 KB (pad 17 -> conflict-free writes)
    __shared__ float Lc[64][65];      // 16.6 KB staged 64x64 L chunk
    __shared__ float Ssh[64 * 17];    // 4.3 KB
    int tid = threadIdx.x;
    int a = tid & 63;                 // row within 64-block
    int g = tid >> 6;                 // rhs group (wave id), 4 rhs per group
    int q0 = blockIdx.x * TRB;
    int qrow[4];
    bool valid[4];
#pragma unroll
    for (int j = 0; j < 4; ++j) {
        int q = q0 + g * 4 + j;
        valid[j] = q < NROWS;
        qrow[j] = valid[j] ? q : 0;
    }
    int db0 = c0 >> 6;

    for (int r = 0; r < LB; ++r) {
        int r0 = r * 64;
        int gcol = c0 + r0;
        float s0 = 0.f, s1 = 0.f, s2 = 0.f, s3 = 0.f;
        for (int kb = 0; kb < r; ++kb) {
            for (int t = tid; t < 4096; t += 256) {
                int i = t >> 6, k = t & 63;
                Lc[i][k] = Lm[(size_t)(gcol + i) * DD + c0 + kb * 64 + k];
            }
            __syncthreads();
            const float* ybase = &Ylds[(kb * 64) * 17 + g * 4];
#pragma unroll 16
            for (int kk = 0; kk < 64; ++kk) {
                float lv = Lc[a][kk];
                const float* yr = ybase + kk * 17;   // wave-uniform broadcast
                s0 += lv * yr[0]; s1 += lv * yr[1];
                s2 += lv * yr[2]; s3 += lv * yr[3];
            }
            __syncthreads();
        }
        // T[a][j] = rhs - S  (rhs read from Trows, coalesced per (g,j))
        Ssh[a * 17 + g * 4 + 0] = (valid[0] ? Trows[(size_t)qrow[0] * DD + gcol + a] : 0.f) - s0;
        Ssh[a * 17 + g * 4 + 1] = (valid[1] ? Trows[(size_t)qrow[1] * DD + gcol + a] : 0.f) - s1;
        Ssh[a * 17 + g * 4 + 2] = (valid[2] ? Trows[(size_t)qrow[2] * DD + gcol + a] : 0.f) - s2;
        Ssh[a * 17 + g * 4 + 3] = (valid[3] ? Trows[(size_t)qrow[3] * DD + gcol + a] : 0.f) - s3;
        __syncthreads();
        // y[a][j] = sum_m Dinv[a][m] * T[m][j];  DinvT layout: [m*64 + a]
        float o0 = 0.f, o1 = 0.f, o2 = 0.f, o3 = 0.f;
        const float* dptr = DinvT + (size_t)(db0 + r) * 4096 + a;
#pragma unroll 8
        for (int m = 0; m < 64; ++m) {
            float dv = dptr[m * 64];                 // 256B coalesced across lanes
            const float* tr = &Ssh[m * 17 + g * 4];  // wave-uniform broadcast
            o0 += dv * tr[0]; o1 += dv * tr[1];
            o2 += dv * tr[2]; o3 += dv * tr[3];
        }
        __syncthreads();   // all Ssh reads done before next step rewrites
        Ylds[(r0 + a) * 17 + g * 4 + 0] = o0;
        Ylds[(r0 + a) * 17 + g * 4 + 1] = o1;
        Ylds[(r0 + a) * 17 + g * 4 + 2] = o2;
        Ylds[(r0 + a) * 17 + g * 4 + 3] = o3;
        if (valid[0]) Trows[(size_t)qrow[0] * DD + gcol + a] = o0;
        if (valid[1]) Trows[(size_t)qrow[1] * DD + gcol + a] = o1;
        if (valid[2]) Trows[(size_t)qrow[2] * DD + gcol + a] = o2;
        if (valid[3]) Trows[(size_t)qrow[3] * DD + gcol + a] = o3;
        __syncthreads();   // Ylds visible before next step's MAC reads
    }
}

// ---------------------------------------------------------------------------
// C[M][Nn] (+/-)= A[M][K] * B[Nn][K]^T  via atomicAdd.
// SPLIT: k-range split over blockIdx.z. NEG: subtract (for TRSM trailing update,
// C holds live RHS -> no memset). lda/ldb/ldc are row strides.
template <int SPLIT, bool NEG>
__global__ __launch_bounds__(256) void gemm_nt(const float* __restrict__ A0,
                                               const float* __restrict__ B,
                                               float* __restrict__ Cc,
                                               int M, int Nn, int K,
                                               int lda, int ldb, int ldc) {
    __shared__ __align__(16) float As[32][68];
    __shared__ __align__(16) float Bs[32][68];
    int bm = blockIdx.x, bn = blockIdx.y, bz = blockIdx.z;
    int row0 = bm * 64, col0 = bn * 64;
    int tid = threadIdx.x;
    int tr = tid >> 4, tc = tid & 15;
    float acc[4][4] = {};
    int nch = K >> 5;
    int klo = 32 * ((bz * nch) / SPLIT);
    int khi = 32 * (((bz + 1) * nch) / SPLIT);
    for (int k0 = klo; k0 < khi; k0 += 32) {
        for (int t = tid; t < 64 * 32; t += 256) {
            int r = t >> 5, kk = t & 31;
            int ar = row0 + r;
            As[kk][r] = (ar < M) ? A0[(size_t)ar * lda + k0 + kk] : 0.f;
            int br = col0 + r;
            Bs[kk][r] = (br < Nn) ? B[(size_t)br * ldb + k0 + kk] : 0.f;
        }
        __syncthreads();
#pragma unroll
        for (int kk = 0; kk < 32; ++kk) {
            float4 av = *(const float4*)(&As[kk][tr << 2]);
            float4 bv = *(const float4*)(&Bs[kk][tc << 2]);
            float a[4] = {av.x, av.y, av.z, av.w};
            float b[4] = {bv.x, bv.y, bv.z, bv.w};
#pragma unroll
            for (int x = 0; x < 4; ++x)
#pragma unroll
                for (int y = 0; y < 4; ++y) acc[x][y] += a[x] * b[y];
        }
        __syncthreads();
    }
#pragma unroll
    for (int x = 0; x < 4; ++x) {
        int r = row0 + tr * 4 + x;
        if (r >= M) continue;
#pragma unroll
        for (int y = 0; y < 4; ++y) {
            int cc2 = col0 + tc * 4 + y;
            if (cc2 < Nn) atomicAdd(&Cc[(size_t)r * ldc + cc2], NEG ? -acc[x][y] : acc[x][y]);
        }
    }
}

// ---------------------------------------------------------------------------
// Vt row (c*18+i): i<16 -> TX[idx], i==16 -> sqrt(kap)*Tm, i==17 -> sqrt(kap+Nc)*Tmu_c
__global__ __launch_bounds__(256) void build_V(const float* __restrict__ Trows,
                                               const int* __restrict__ cls_idx,
                                               const int* __restrict__ cls_n,
                                               const float* __restrict__ kappa,
                                               float* __restrict__ Vt) {
    int row = blockIdx.x;
    int c = row / RR, i = row % RR;
    int cnt = cls_n[c];
    float kap = fabsf(kappa[0]) + 1e-6f;
    size_t srow;
    float sc = 1.f;
    if (i < SHOT) {
        if (i >= cnt) {
            for (int d = threadIdx.x; d < DD; d += 256) Vt[(size_t)row * DD + d] = 0.f;
            return;
        }
        srow = (size_t)NQQ + cls_idx[c * SHOT + i];
    } else if (i == SHOT) {
        srow = NQQ + NSUP;
        sc = sqrtf(kap);
    } else {
        srow = (size_t)NQQ + NSUP + 1 + c;
        sc = sqrtf(kap + (float)cnt);
    }
    for (int d = threadIdx.x; d < DD; d += 256)
        Vt[(size_t)row * DD + d] = sc * Trows[srow * DD + d];
}

// ---------------------------------------------------------------------------
// per class: M = J + Vt Vt^T (fp64), invert (GJ w/ pivoting, fp64), h, consts.
__global__ __launch_bounds__(256) void build_M(const float* __restrict__ Trows,
                                               const float* __restrict__ mmu,
                                               const float* __restrict__ Vt,
                                               const float* __restrict__ tdiag,
                                               const float* __restrict__ kappa,
                                               const float* __restrict__ nu,
                                               const int* __restrict__ cls_n,
                                               float* __restrict__ consts,
                                               float* __restrict__ hbuf,
                                               float* __restrict__ MinvO) {
    int c = blockIdx.x;
    __shared__ double Md[RR][RR];
    __shared__ double aug[RR][2 * RR];
    __shared__ double colk[RR];
    __shared__ double red[4];
    __shared__ double gj_logdet;
    __shared__ float hs[RR];
    __shared__ float ng2t_s, mu2_s;
    int tid = threadIdx.x;
    int wave = tid >> 6, lane = tid & 63;
    const float* Vc = Vt + (size_t)c * RR * DD;
    const float* Tmu = Trows + (size_t)(NQQ + NSUP + 1 + c) * DD;
    const float* mu_raw = mmu + (size_t)(1 + c) * DD;

    for (int p = wave; p < RR * RR + RR + 2; p += 4) {
        const float *va, *vb;
        if (p < RR * RR) {
            int i = p / RR, j = p % RR;
            if (i > j) continue;
            va = Vc + (size_t)i * DD; vb = Vc + (size_t)j * DD;
        } else if (p < RR * RR + RR) {
            va = Vc + (size_t)(p - RR * RR) * DD; vb = Tmu;
        } else if (p == RR * RR + RR) {
            va = Tmu; vb = Tmu;
        } else {
            va = mu_raw; vb = mu_raw;
        }
        double s = 0.0;
        for (int d = lane; d < DD; d += 64) s += (double)va[d] * (double)vb[d];
        for (int off = 32; off; off >>= 1) s += __shfl_down(s, off);
        if (lane == 0) {
            if (p < RR * RR) { int i = p / RR, j = p % RR; Md[i][j] = s; Md[j][i] = s; }
            else if (p < RR * RR + RR) hs[p - RR * RR] = (float)s;
            else if (p == RR * RR + RR) ng2t_s = (float)s;
            else mu2_s = (float)s;
        }
    }
    double sl = 0.0;
    for (int k = tid; k < DD; k += 256) sl += log((double)fabsf(tdiag[k]));
    for (int off = 32; off; off >>= 1) sl += __shfl_down(sl, off);
    if (lane == 0) red[wave] = sl;
    __syncthreads();

    if (tid == 0) {
        for (int i = 0; i < RR - 1; ++i) Md[i][i] += 1.0;
        Md[RR - 1][RR - 1] -= 1.0;
        gj_logdet = 0.0;
    }
    __syncthreads();
    for (int t = tid; t < RR * 2 * RR; t += 256) {
        int r2 = t / (2 * RR), j2 = t % (2 * RR);
        aug[r2][j2] = (j2 < RR) ? Md[r2][j2] : ((j2 - RR == r2) ? 1.0 : 0.0);
    }
    __syncthreads();
    for (int k = 0; k < RR; ++k) {
        if (tid == 0) {
            int piv = k; double best = fabs(aug[k][k]);
            for (int r2 = k + 1; r2 < RR; ++r2) {
                double v = fabs(aug[r2][k]);
                if (v > best) { best = v; piv = r2; }
            }
            if (piv != k) {
                for (int j2 = 0; j2 < 2 * RR; ++j2) {
                    double tmp = aug[k][j2]; aug[k][j2] = aug[piv][j2]; aug[piv][j2] = tmp;
                }
            }
            double pv = aug[k][k];
            gj_logdet += log(fabs(pv));
            double inv = 1.0 / pv;
            for (int j2 = 0; j2 < 2 * RR; ++j2) aug[k][j2] *= inv;
        }
        __syncthreads();
        if (tid < RR) colk[tid] = (tid == k) ? 0.0 : aug[tid][k];
        __syncthreads();
        for (int t = tid; t < RR * 2 * RR; t += 256) {
            int r2 = t / (2 * RR), j2 = t % (2 * RR);
            if (r2 != k) aug[r2][j2] -= colk[r2] * aug[k][j2];
        }
        __syncthreads();
    }
    if (tid == 0) {
        double sumlog = red[0] + red[1] + red[2] + red[3];
        double kap = fabs((double)kappa[0]) + 1e-6;
        double nu_ = fmax((double)nu[0], (double)(DD - 1) + 1e-6);
        double fn = (double)cls_n[c];
        double common = nu_ + fn + 1.0 - (double)DD;
        double scale = (kap + fn + 1.0) / (common * (kap + fn));
        double logdet_sigma = (double)DD * log(scale) + 2.0 * sumlog + gj_logdet;
        double bias = lgamma(0.5 * (common + DD)) - lgamma(0.5 * common)
                    - 0.5 * DD * log(common) - 0.5 * logdet_sigma;
        consts[c * 8 + 0] = (float)((1.0 - (double)REGP) / scale);
        consts[c * 8 + 1] = (float)common;
        consts[c * 8 + 2] = (float)(0.5 * (common + DD));
        consts[c * 8 + 3] = (float)bias;
        consts[c * 8 + 4] = (float)(1.0 / sqrt(kap + fn));
        consts[c * 8 + 5] = ng2t_s;
        consts[c * 8 + 6] = mu2_s;
        consts[c * 8 + 7] = 0.f;
    }
    __syncthreads();
    for (int t = tid; t < RR * RR; t += 256)
        MinvO[(size_t)c * RR * RR + t] = (float)aug[t / RR][RR + t % RR];
    if (tid < RR) hbuf[c * RR + tid] = hs[tid];
}

// ---------------------------------------------------------------------------
__global__ __launch_bounds__(256) void query_norms(const float* __restrict__ Qx,
                                                   const float* __restrict__ Trows,
                                                   float* __restrict__ q2,
                                                   float* __restrict__ nq2t) {
    int q = blockIdx.x * 4 + (threadIdx.x >> 6);
    int lane = threadIdx.x & 63;
    float s1 = 0.f, s2 = 0.f;
    for (int d = lane; d < DD; d += 64) {
        float a = Qx[(size_t)q * DD + d]; s1 += a * a;
        float b = Trows[(size_t)q * DD + d]; s2 += b * b;
    }
    for (int off = 32; off; off >>= 1) { s1 += __shfl_down(s1, off); s2 += __shfl_down(s2, off); }
    if (lane == 0) { q2[q] = s1; nq2t[q] = s2; }
}

// ---------------------------------------------------------------------------
__global__ __launch_bounds__(256) void final_kernel(const float* __restrict__ P,
                                                    const float* __restrict__ dotqmu,
                                                    const float* __restrict__ q2,
                                                    const float* __restrict__ nq2t,
                                                    const float* __restrict__ consts,
                                                    const float* __restrict__ hbuf,
                                                    const float* __restrict__ Minv,
                                                    float* __restrict__ out) {
    int c = blockIdx.x, qt = blockIdx.y;
    __shared__ float Ms[RR][RR];
    __shared__ float hlds[RR];
    __shared__ float cs[8];
    int tid = threadIdx.x;
    for (int t = tid; t < RR * RR; t += 256) Ms[t / RR][t % RR] = Minv[(size_t)c * RR * RR + t];
    if (tid < RR) hlds[tid] = hbuf[c * RR + tid];
    if (tid < 8) cs[tid] = consts[c * 8 + tid];
    __syncthreads();
    int q = qt * 256 + tid;
    const float* Pq = P + (size_t)q * (NC * RR) + c * RR;
    float p[RR];
    float p17raw = Pq[RR - 1];
#pragma unroll
    for (int i = 0; i < RR; ++i) p[i] = Pq[i] - hlds[i];
    float quad = 0.f;
#pragma unroll
    for (int i = 0; i < RR; ++i) {
        float t = 0.f;
#pragma unroll
        for (int j = 0; j < RR; ++j) t += Ms[i][j] * p[j];
        quad += p[i] * t;
    }
    float w1 = cs[0], common = cs[1], coef = cs[2], bias = cs[3];
    float inv_s17 = cs[4], ng2t = cs[5], mu2 = cs[6];
    float Gu2 = nq2t[q] - 2.f * p17raw * inv_s17 + ng2t;
    float u2 = q2[q] - 2.f * dotqmu[(size_t)q * NC + c] + mu2;
    float dist = w1 * (Gu2 - quad) + REGP * u2;
    out[(size_t)q * NC + c] = bias - coef * log1pf(dist / common);
}

// ---------------------------------------------------------------------------
extern "C" void kernel_launch(void* const* d_in, const int* in_sizes, int n_in,
                              void* d_out, int out_size, void* d_ws, size_t ws_size,
                              hipStream_t stream) {
    const float* Xs    = (const float*)d_in[0];
    const float* Qx    = (const float*)d_in[1];
    const float* m     = (const float*)d_in[2];
    const float* kappa = (const float*)d_in[3];
    const float* nu    = (const float*)d_in[4];
    const float* tdiag = (const float*)d_in[5];
    const float* tlow  = (const float*)d_in[6];
    const int* labels  = (const int*)d_in[7];
    float* out = (float*)d_out;

    float* ws = (float*)d_ws;
    float* Lm     = ws;                                  // D*D
    float* mmu    = Lm + DDS;                            // (NC+1)*D  [m; mu_0..63]
    float* DinvT  = mmu + (size_t)(NC + 1) * DD;         // 12*64*64 (transposed diag inverses)
    float* Trows  = DinvT + (size_t)NDB * 64 * 64;       // NROWS*D (stacked rhs -> solved in place)
    float* Vt     = Trows + (size_t)NROWS * DD;          // NC*RR*D
    float* P      = Vt + (size_t)NC * RR * DD;           // NQ*NC*RR
    float* dotqmu = P + (size_t)NQQ * NC * RR;           // NQ*NC   (contiguous after P)
    float* q2     = dotqmu + (size_t)NQQ * NC;           // NQ
    float* nq2t   = q2 + NQQ;                            // NQ
    float* consts = nq2t + NQQ;                          // NC*8
    float* hbuf   = consts + NC * 8;                     // NC*RR
    float* MinvB  = hbuf + NC * RR;                      // NC*RR*RR
    int* cls_idx  = (int*)(MinvB + (size_t)NC * RR * RR);// NC*SHOT
    int* cls_n    = cls_idx + NC * SHOT;                 // NC

    // zero only the atomic-accumulated outputs (P + dotqmu contiguous)
    hipMemsetAsync(P, 0, ((size_t)NQQ * NC * RR + (size_t)NQQ * NC) * sizeof(float), stream);

    build_L<<<(DDS + 255) / 256, 256, 0, stream>>>(tdiag, tlow, Lm);
    class_stats<<<NC, 256, 0, stream>>>(Xs, m, labels, kappa, mmu, cls_idx, cls_n);
    diag_inv64<<<NDB, 64, 0, stream>>>(Lm, DinvT);
    copy_stack<<<(NROWS * (DD / 4) + 255) / 256, 256, 0, stream>>>(Qx, Xs, mmu, Trows);
    // two-level blocked TRSM: leaf solve | trailing GEMM update | leaf solve
    leaf_trsm<<<NTB, 256, 0, stream>>>(Trows, Lm, DinvT, 0);
    gemm_nt<2, true><<<dim3((NROWS + 63) / 64, LW / 64, 2), 256, 0, stream>>>(
        Trows, Lm + (size_t)LW * DD, Trows + LW, NROWS, LW, LW, DD, DD, DD);
    leaf_trsm<<<NTB, 256, 0, stream>>>(Trows, Lm, DinvT, LW);
    build_V<<<NC * RR, 256, 0, stream>>>(Trows, cls_idx, cls_n, kappa, Vt);
    build_M<<<NC, 256, 0, stream>>>(Trows, mmu, Vt, tdiag, kappa, nu, cls_n, consts, hbuf, MinvB);
    query_norms<<<NQQ / 4, 256, 0, stream>>>(Qx, Trows, q2, nq2t);
    gemm_nt<3, false><<<dim3(NQQ / 64, (NC * RR) / 64, 3), 256, 0, stream>>>(
        Trows, Vt, P, NQQ, NC * RR, DD, DD, DD, NC * RR);
    gemm_nt<4, false><<<dim3(NQQ / 64, 1, 4), 256, 0, stream>>>(
        Qx, mmu + DD, dotqmu, NQQ, NC, DD, DD, DD, NC);
    final_kernel<<<dim3(NC, NQQ / 256), 256, 0, stream>>>(P, dotqmu, q2, nq2t, consts, hbuf, MinvB, out);
}